// Round 1
// baseline (106.204 us; speedup 1.0000x reference)
//
#include <hip/hip_runtime.h>
#include <hip/hip_bf16.h>

#define NB 64
#define CD 128
#define LL 4096
#define LCHUNK 64
#define NSUB 4
#define P1_NBLK 16     // LL/(LCHUNK*NSUB)
#define P3_NCHUNK 64   // LL/LCHUNK

typedef __attribute__((ext_vector_type(8))) short short8;
typedef __attribute__((ext_vector_type(4))) float f32x4;

// ws layout (bytes)
#define WT_OFF   0                                 // 3*128*128 bf16 = 98304 B
#define WSM_OFF  131072
#define WSS_OFF  (WSM_OFF + NB*P1_NBLK*CD*4)
#define WSP_OFF  (WSS_OFF + NB*P1_NBLK*CD*4)
#define POOL_OFF (WSP_OFF + NB*P1_NBLK*CD*4)

__device__ __forceinline__ unsigned short f2bf(float f) {
    union { float f; unsigned u; } v; v.f = f;
    unsigned r = v.u + 0x7FFFu + ((v.u >> 16) & 1u);
    return (unsigned short)(r >> 16);
}

// W[t] is [C=128][D=128]; produce wt[t][d][c] = bf16(W[c][d])  (i.e. W^T, c contiguous)
__global__ void prep_wt(const float* __restrict__ Wq, const float* __restrict__ Wk,
                        const float* __restrict__ Wv, unsigned short* __restrict__ wt) {
    int t = blockIdx.x >> 7;
    int d = blockIdx.x & 127;
    const float* W = (t == 0) ? Wq : (t == 1) ? Wk : Wv;
    int c = threadIdx.x;
    wt[((size_t)t*CD + d)*CD + c] = f2bf(W[c*CD + d]);
}

// ---------------- pass 1: K,V GEMM + online-softmax partials ----------------
__global__ __launch_bounds__(256, 2)
void aft_pass1(const float* __restrict__ x, const unsigned short* __restrict__ wt,
               const float* __restrict__ bk, const float* __restrict__ bv,
               float* __restrict__ wsM, float* __restrict__ wsS, float* __restrict__ wsP) {
    __shared__ unsigned short lds_x[LCHUNK * 136];   // [l][c], c padded 128->136 (keeps 16B align)
    const int tid = threadIdx.x;
    const int n = blockIdx.x >> 4;
    const int blk = blockIdx.x & 15;
    const int w = tid >> 6, lane = tid & 63, r = lane & 15, g = lane >> 4;

    // A fragments: lane holds W^T[d = base + r][c = 32*s + 8*g .. +7]
    short8 a_k[2][4], a_v[2][4];
#pragma unroll
    for (int rt = 0; rt < 2; ++rt)
#pragma unroll
        for (int s = 0; s < 4; ++s) {
            int d = 32*w + 16*rt + r;
            a_k[rt][s] = *(const short8*)(wt + ((size_t)(1*CD + d))*CD + 32*s + 8*g);
            a_v[rt][s] = *(const short8*)(wt + ((size_t)(2*CD + d))*CD + 32*s + 8*g);
        }

    f32x4 bkv[2], bvv[2];
#pragma unroll
    for (int rt = 0; rt < 2; ++rt) {
        bkv[rt] = *(const f32x4*)(bk + 32*w + 16*rt + 4*g);
        bvv[rt] = *(const f32x4*)(bv + 32*w + 16*rt + 4*g);
    }

    float m_run[2][4], s_run[2][4], p_run[2][4];
#pragma unroll
    for (int rt = 0; rt < 2; ++rt)
#pragma unroll
        for (int v = 0; v < 4; ++v) { m_run[rt][v] = -1e30f; s_run[rt][v] = 0.f; p_run[rt][v] = 0.f; }

    for (int sub = 0; sub < NSUB; ++sub) {
        const int l0 = (blk*NSUB + sub) * LCHUNK;
        __syncthreads();
        // stage X[n][:, l0:l0+64] -> LDS transposed bf16
        {
            const int cc = tid >> 4, f = tid & 15;
#pragma unroll
            for (int it = 0; it < 8; ++it) {
                int c = cc + 16*it;
                f32x4 xv = *(const f32x4*)(x + ((size_t)n*CD + c)*LL + l0 + 4*f);
                int l = 4*f;
                lds_x[(l+0)*136 + c] = f2bf(xv[0]);
                lds_x[(l+1)*136 + c] = f2bf(xv[1]);
                lds_x[(l+2)*136 + c] = f2bf(xv[2]);
                lds_x[(l+3)*136 + c] = f2bf(xv[3]);
            }
        }
        __syncthreads();

        f32x4 acc_k[2][4], acc_v[2][4];
#pragma unroll
        for (int rt = 0; rt < 2; ++rt)
#pragma unroll
            for (int ct = 0; ct < 4; ++ct) {
                acc_k[rt][ct] = (f32x4){0.f,0.f,0.f,0.f};
                acc_v[rt][ct] = (f32x4){0.f,0.f,0.f,0.f};
            }

#pragma unroll
        for (int s = 0; s < 4; ++s) {
#pragma unroll
            for (int ct = 0; ct < 4; ++ct) {
                short8 b = *(const short8*)(lds_x + (ct*16 + r)*136 + 32*s + 8*g);
                acc_k[0][ct] = __builtin_amdgcn_mfma_f32_16x16x32_bf16(a_k[0][s], b, acc_k[0][ct], 0,0,0);
                acc_k[1][ct] = __builtin_amdgcn_mfma_f32_16x16x32_bf16(a_k[1][s], b, acc_k[1][ct], 0,0,0);
                acc_v[0][ct] = __builtin_amdgcn_mfma_f32_16x16x32_bf16(a_v[0][s], b, acc_v[0][ct], 0,0,0);
                acc_v[1][ct] = __builtin_amdgcn_mfma_f32_16x16x32_bf16(a_v[1][s], b, acc_v[1][ct], 0,0,0);
            }
        }

        // online softmax reduce over this 64-l chunk (4 ct in-lane + 16 lanes of group)
#pragma unroll
        for (int rt = 0; rt < 2; ++rt) {
#pragma unroll
            for (int v = 0; v < 4; ++v) {
                float k0 = acc_k[rt][0][v] + bkv[rt][v];
                float k1 = acc_k[rt][1][v] + bkv[rt][v];
                float k2 = acc_k[rt][2][v] + bkv[rt][v];
                float k3 = acc_k[rt][3][v] + bkv[rt][v];
                float v0 = acc_v[rt][0][v] + bvv[rt][v];
                float v1 = acc_v[rt][1][v] + bvv[rt][v];
                float v2 = acc_v[rt][2][v] + bvv[rt][v];
                float v3 = acc_v[rt][3][v] + bvv[rt][v];
                float m = fmaxf(fmaxf(k0,k1), fmaxf(k2,k3));
                m = fmaxf(m, __shfl_xor(m, 1, 64));
                m = fmaxf(m, __shfl_xor(m, 2, 64));
                m = fmaxf(m, __shfl_xor(m, 4, 64));
                m = fmaxf(m, __shfl_xor(m, 8, 64));
                float e0 = __expf(k0 - m), e1 = __expf(k1 - m);
                float e2 = __expf(k2 - m), e3 = __expf(k3 - m);
                float sl = (e0 + e1) + (e2 + e3);
                float pl = e0*v0 + e1*v1 + e2*v2 + e3*v3;
                sl += __shfl_xor(sl, 1, 64); pl += __shfl_xor(pl, 1, 64);
                sl += __shfl_xor(sl, 2, 64); pl += __shfl_xor(pl, 2, 64);
                sl += __shfl_xor(sl, 4, 64); pl += __shfl_xor(pl, 4, 64);
                sl += __shfl_xor(sl, 8, 64); pl += __shfl_xor(pl, 8, 64);
                float mo = m_run[rt][v];
                float mn = fmaxf(mo, m);
                float au = __expf(mo - mn);
                float bu = __expf(m - mn);
                s_run[rt][v] = s_run[rt][v]*au + sl*bu;
                p_run[rt][v] = p_run[rt][v]*au + pl*bu;
                m_run[rt][v] = mn;
            }
        }
    }

    if (r == 0) {
#pragma unroll
        for (int rt = 0; rt < 2; ++rt)
#pragma unroll
            for (int v = 0; v < 4; ++v) {
                int d = 32*w + 16*rt + 4*g + v;
                size_t idx = ((size_t)n*P1_NBLK + blk)*CD + d;
                wsM[idx] = m_run[rt][v];
                wsS[idx] = s_run[rt][v];
                wsP[idx] = p_run[rt][v];
            }
    }
}

// ---------------- pass 2: combine partials -> pooled[n][d] ----------------
__global__ void aft_pass2(const float* __restrict__ wsM, const float* __restrict__ wsS,
                          const float* __restrict__ wsP, float* __restrict__ pooled) {
    int n = blockIdx.x, d = threadIdx.x;
    float m = -1e30f, s = 0.f, p = 0.f;
    for (int b = 0; b < P1_NBLK; ++b) {
        size_t idx = ((size_t)n*P1_NBLK + b)*CD + d;
        float mb = wsM[idx], sb = wsS[idx], pb = wsP[idx];
        float mn = fmaxf(m, mb);
        float au = __expf(m - mn), bu = __expf(mb - mn);
        s = s*au + sb*bu;
        p = p*au + pb*bu;
        m = mn;
    }
    pooled[(size_t)n*CD + d] = p / s;
}

// ---------------- pass 3: Q GEMM + sigmoid*pooled, coalesced store ----------------
__global__ __launch_bounds__(256, 2)
void aft_pass3(const float* __restrict__ x, const unsigned short* __restrict__ wt,
               const float* __restrict__ bq, const float* __restrict__ pooled,
               float* __restrict__ out) {
    __shared__ unsigned short lds_x[LCHUNK * 136];
    __shared__ float lds_o[CD * 68];
    const int tid = threadIdx.x;
    const int n = blockIdx.x >> 6;
    const int ch = blockIdx.x & 63;
    const int l0 = ch * LCHUNK;
    const int w = tid >> 6, lane = tid & 63, r = lane & 15, g = lane >> 4;

    short8 a_q[2][4];
#pragma unroll
    for (int rt = 0; rt < 2; ++rt)
#pragma unroll
        for (int s = 0; s < 4; ++s) {
            int d = 32*w + 16*rt + r;
            a_q[rt][s] = *(const short8*)(wt + ((size_t)(0*CD + d))*CD + 32*s + 8*g);
        }

    // stage X
    {
        const int cc = tid >> 4, f = tid & 15;
#pragma unroll
        for (int it = 0; it < 8; ++it) {
            int c = cc + 16*it;
            f32x4 xv = *(const f32x4*)(x + ((size_t)n*CD + c)*LL + l0 + 4*f);
            int l = 4*f;
            lds_x[(l+0)*136 + c] = f2bf(xv[0]);
            lds_x[(l+1)*136 + c] = f2bf(xv[1]);
            lds_x[(l+2)*136 + c] = f2bf(xv[2]);
            lds_x[(l+3)*136 + c] = f2bf(xv[3]);
        }
    }
    __syncthreads();

    f32x4 acc[2][4];
#pragma unroll
    for (int rt = 0; rt < 2; ++rt)
#pragma unroll
        for (int ct = 0; ct < 4; ++ct) acc[rt][ct] = (f32x4){0.f,0.f,0.f,0.f};

#pragma unroll
    for (int s = 0; s < 4; ++s) {
#pragma unroll
        for (int ct = 0; ct < 4; ++ct) {
            short8 b = *(const short8*)(lds_x + (ct*16 + r)*136 + 32*s + 8*g);
            acc[0][ct] = __builtin_amdgcn_mfma_f32_16x16x32_bf16(a_q[0][s], b, acc[0][ct], 0,0,0);
            acc[1][ct] = __builtin_amdgcn_mfma_f32_16x16x32_bf16(a_q[1][s], b, acc[1][ct], 0,0,0);
        }
    }

    f32x4 bqv[2], plv[2];
#pragma unroll
    for (int rt = 0; rt < 2; ++rt) {
        bqv[rt] = *(const f32x4*)(bq + 32*w + 16*rt + 4*g);
        plv[rt] = *(const f32x4*)(pooled + (size_t)n*CD + 32*w + 16*rt + 4*g);
    }

#pragma unroll
    for (int rt = 0; rt < 2; ++rt)
#pragma unroll
        for (int ct = 0; ct < 4; ++ct)
#pragma unroll
            for (int v = 0; v < 4; ++v) {
                float q = acc[rt][ct][v] + bqv[rt][v];
                float o = plv[rt][v] / (1.f + __expf(-q));
                int d = 32*w + 16*rt + 4*g + v;
                lds_o[d*68 + ct*16 + r] = o;
            }
    __syncthreads();

    // coalesced fp32 store: full rows of 64 l per d
    {
        const int f = tid & 15;
#pragma unroll
        for (int it = 0; it < 8; ++it) {
            int row = (tid >> 4) + 16*it;
            f32x4 val = *(const f32x4*)(lds_o + row*68 + 4*f);
            *(f32x4*)(out + ((size_t)n*CD + row)*LL + l0 + 4*f) = val;
        }
    }
}

extern "C" void kernel_launch(void* const* d_in, const int* in_sizes, int n_in,
                              void* d_out, int out_size, void* d_ws, size_t ws_size,
                              hipStream_t stream) {
    const float* x  = (const float*)d_in[0];
    const float* Wq = (const float*)d_in[1];
    const float* bq = (const float*)d_in[2];
    const float* Wk = (const float*)d_in[3];
    const float* bk = (const float*)d_in[4];
    const float* Wv = (const float*)d_in[5];
    const float* bv = (const float*)d_in[6];
    float* out = (float*)d_out;
    char* ws = (char*)d_ws;
    unsigned short* wt = (unsigned short*)(ws + WT_OFF);
    float* wsM = (float*)(ws + WSM_OFF);
    float* wsS = (float*)(ws + WSS_OFF);
    float* wsP = (float*)(ws + WSP_OFF);
    float* pooled = (float*)(ws + POOL_OFF);

    prep_wt<<<384, 128, 0, stream>>>(Wq, Wk, Wv, wt);
    aft_pass1<<<NB * P1_NBLK, 256, 0, stream>>>(x, wt, bk, bv, wsM, wsS, wsP);
    aft_pass2<<<NB, CD, 0, stream>>>(wsM, wsS, wsP, pooled);
    aft_pass3<<<NB * P3_NCHUNK, 256, 0, stream>>>(x, wt, bq, pooled, out);
}